// Round 8
// baseline (225.676 us; speedup 1.0000x reference)
//
#include <hip/hip_runtime.h>
#include <math.h>

// LinearAttention B=4, S=2048, D=1024 — bf16 MFMA.
// R8: associativity — out = qp @ (kp^T @ vp). M=kp^T@vp is [4,1024,1024] bf16;
// same FLOPs as attn@vp (S=2D) but kills the 66us out-GEMM AND the attnB
// bf16 copy (33.5MB write + 33.5MB read). attn (required output) unchanged.
// Numerics: qp rows sum to 1, M entries ~1e-5 -> bf16-M adds <~3e-8 abs to out.
// proj: gemm_bw BM=128 @ 3 blocks/CU (48KB LDS) for deeper latency hiding.
//   proj: BM=128, grid 8x64x3 = 1536 blocks (2 rounds @ 3/CU)
//   Mt  : BM=128, grid 8x8x4  = 256 blocks  (K=2048)
//   attn: 256x256 4-phase, grid 8x8x4 = 256 blocks (fp32-only epilogue)
//   out2: BM=128, grid 8x16x4 = 512 blocks  (K=1024)
//
// Workspace map (u16 elems):
//   R0 [0,        8388608): qE  (exp'd q logits -> qp bf16)
//   R1 [8388608, 16777216): kE  (-> kp, normalized in place by norm_all)
//   R2 [16777216,25165824): Wqb@+0, Wkb@+1M, Wvb@+2M (dead after proj)
//   R3 [25165824,33554432): qb (dead after proj) -> vpT [4,1024,2048]
//   R4 [33554432,50331648): kb|vb (dead after proj) -> kpT@+0 [4,1024,2048],
//                           Mt@+8.4M [4,1024,1024]
//   tail @ 50331648 (floats): kpart, vpart, kinv, vinv, biasCat[3][1024]
//   vE lives in d_out's attn region (dead before attn GEMM overwrites it).

typedef float  f32x4  __attribute__((ext_vector_type(4)));
typedef __bf16 bf16x8 __attribute__((ext_vector_type(8)));
typedef int    i32x4  __attribute__((ext_vector_type(4)));
typedef unsigned short u16;

__device__ __forceinline__ float b2f(u16 u) {
    unsigned int i = ((unsigned int)u) << 16; float f;
    __builtin_memcpy(&f, &i, 4); return f;
}
__device__ __forceinline__ u16 f2b(float f) {  // round-to-nearest-even
    unsigned int i; __builtin_memcpy(&i, &f, 4);
    i += 0x7FFFu + ((i >> 16) & 1u);
    return (u16)(i >> 16);
}

// ---- mega convert: q,k,v,Wq,Wk,Wv fp32->bf16 + bias gather -----------------
__global__ __launch_bounds__(256) void cvt_all(
    const float4* __restrict__ q, const float4* __restrict__ k,
    const float4* __restrict__ v, const float4* __restrict__ Wq,
    const float4* __restrict__ Wk, const float4* __restrict__ Wv,
    const float* __restrict__ bq, const float* __restrict__ bk,
    const float* __restrict__ bv,
    ushort4* __restrict__ qb, ushort4* __restrict__ kb,
    ushort4* __restrict__ vb, ushort4* __restrict__ Wb,
    float* __restrict__ biasCat)
{
    int bid = blockIdx.x, t = threadIdx.x;
    const float4* s; ushort4* d; int idx;
    if (bid < 8192)       { s = q;  d = qb;            idx = bid * 256 + t; }
    else if (bid < 16384) { s = k;  d = kb;            idx = (bid - 8192) * 256 + t; }
    else if (bid < 24576) { s = v;  d = vb;            idx = (bid - 16384) * 256 + t; }
    else if (bid < 25600) { s = Wq; d = Wb;            idx = (bid - 24576) * 256 + t; }
    else if (bid < 26624) { s = Wk; d = Wb + 262144;   idx = (bid - 25600) * 256 + t; }
    else if (bid < 27648) { s = Wv; d = Wb + 524288;   idx = (bid - 26624) * 256 + t; }
    else {
        for (int i = t; i < 3072; i += 256)
            biasCat[i] = (i < 1024) ? bq[i] : (i < 2048) ? bk[i - 1024] : bv[i - 2048];
        return;
    }
    float4 vv = s[idx];
    ushort4 o;
    o.x = f2b(vv.x); o.y = f2b(vv.y); o.z = f2b(vv.z); o.w = f2b(vv.w);
    d[idx] = o;
}

// ===========================================================================
// 256x256 4-phase TN GEMM (attn). fp32-only epilogue (attnB dropped in R8).
// ===========================================================================
__global__ __launch_bounds__(512, 2) void gemm256_attn(
    const u16* __restrict__ Ap, const u16* __restrict__ Bp,
    float* __restrict__ C32,
    int N, int K, long long sA, long long sB, long long sC)
{
    __shared__ __align__(16) u16 lds[65536];   // 128 KiB

    const int tid  = threadIdx.x;
    const int lane = tid & 63;
    const int w    = tid >> 6;
    const int wr   = w >> 2, wc = w & 3;

    const int gx  = gridDim.x;
    const int tot = gx * gridDim.y;
    const int lin = blockIdx.y * gx + blockIdx.x;
    const int vlin = (lin & 7) * (tot >> 3) + (lin >> 3);
    const int bx = vlin % gx, by = vlin / gx;
    const int m0 = by * 256, n0 = bx * 256;
    const int z  = blockIdx.z;

    const u16* Ag = Ap + (size_t)z * sA;
    const u16* Bg = Bp + (size_t)z * sB;

    const int cl = tid ^ ((tid >> 4) & 6);
    const int lr = cl >> 3;
    const int ce = (cl & 7) * 8;
    const int arow = m0 + lr;
    const int brow = n0 + (lr & 31) + ((lr & 32) << 1);

    const int axr = ((lane >> 2) & 3) << 4;
    const int ar0 = (wr * 64 + (lane & 15)) * 64 + (lane >> 4) * 8;
    const int br0 = (wc * 32 + (lane & 15)) * 64 + (lane >> 4) * 8;

#define GLL16(gsrc, ldsoff)                                                    \
    __builtin_amdgcn_global_load_lds(                                          \
        (__attribute__((address_space(1))) void*)(uintptr_t)(gsrc),            \
        (__attribute__((address_space(3))) void*)&lds[ldsoff], 16, 0, 0)

#define STAGE_A(c, h, T)                                                       \
    do { const u16* _s = Ag + (size_t)(arow + (h) * 64) * K + (T) * 64 + ce;   \
         int _d = (((c) << 1) + (h)) * 8192 + tid * 8;                         \
         GLL16(_s, _d); GLL16(_s + (size_t)128 * K, _d + 4096); } while (0)

#define STAGE_B(c, g, T)                                                       \
    do { const u16* _s = Bg + (size_t)(brow + (g) * 32) * K + (T) * 64 + ce;   \
         int _d = 32768 + (((c) << 1) + (g)) * 8192 + tid * 8;                 \
         GLL16(_s, _d); GLL16(_s + (size_t)128 * K, _d + 4096); } while (0)

#define SBAR asm volatile("s_barrier" ::: "memory")
#define LGKM0 do { asm volatile("s_waitcnt lgkmcnt(0)" ::: "memory");          \
                   __builtin_amdgcn_sched_barrier(0); } while (0)

#define LDA(base)                                                              \
    _Pragma("unroll") for (int mi2 = 0; mi2 < 4; ++mi2)                        \
    _Pragma("unroll") for (int ks = 0; ks < 2; ++ks)                           \
        afr[mi2][ks] = __builtin_bit_cast(bf16x8,                              \
            *(const i32x4*)&lds[(base) + ((ar0 + mi2 * 1024 + ks * 32) ^ axr)]);

#define LDB(dst, base)                                                         \
    _Pragma("unroll") for (int ni2 = 0; ni2 < 2; ++ni2)                        \
    _Pragma("unroll") for (int ks = 0; ks < 2; ++ks)                           \
        dst[ni2][ks] = __builtin_bit_cast(bf16x8,                              \
            *(const i32x4*)&lds[(base) + ((br0 + ni2 * 1024 + ks * 32) ^ axr)]);

#define MFMA_Q(mb, nb, bfrag)                                                  \
    __builtin_amdgcn_s_setprio(1);                                             \
    _Pragma("unroll") for (int mi2 = 0; mi2 < 4; ++mi2)                        \
    _Pragma("unroll") for (int ni2 = 0; ni2 < 2; ++ni2)                        \
    _Pragma("unroll") for (int ks = 0; ks < 2; ++ks)                           \
        acc[(mb) + mi2][(nb) + ni2] = __builtin_amdgcn_mfma_f32_16x16x32_bf16( \
            afr[mi2][ks], bfrag[ni2][ks], acc[(mb) + mi2][(nb) + ni2], 0, 0, 0); \
    __builtin_amdgcn_s_setprio(0)

    f32x4 acc[8][4];
#pragma unroll
    for (int i = 0; i < 8; ++i)
#pragma unroll
        for (int j = 0; j < 4; ++j) acc[i][j] = (f32x4)0.0f;

    bf16x8 afr[4][2], b0f[2][2], b1f[2][2];

    const int nt = K >> 6;

    STAGE_A(0, 0, 0); STAGE_B(0, 0, 0);
    STAGE_A(0, 1, 0); STAGE_B(0, 1, 0);
    STAGE_A(1, 0, 1); STAGE_B(1, 0, 1);

    for (int T = 0; T < nt; ++T) {
        const int cur = T & 1, nxt = cur ^ 1;
        const int ab = (cur << 1) * 8192;
        const int bb = 32768 + (cur << 1) * 8192;

        if (T + 1 < nt) asm volatile("s_waitcnt vmcnt(4)" ::: "memory");
        else            asm volatile("s_waitcnt vmcnt(0)" ::: "memory");
        SBAR;
        LDA(ab); LDB(b0f, bb);
        if (T + 1 < nt) STAGE_B(nxt, 1, T + 1);
        SBAR; LGKM0;
        MFMA_Q(0, 0, b0f);
        SBAR;
        LDB(b1f, bb + 8192);
        if (T + 1 < nt) STAGE_A(nxt, 1, T + 1);
        SBAR; LGKM0;
        MFMA_Q(0, 2, b1f);
        SBAR;
        LDA(ab + 8192);
        if (T + 2 < nt) STAGE_A(cur, 0, T + 2);
        SBAR; LGKM0;
        MFMA_Q(4, 0, b0f);
        SBAR;
        if (T + 2 < nt) STAGE_B(cur, 0, T + 2);
        SBAR; LGKM0;
        MFMA_Q(4, 2, b1f);
        SBAR;
    }

    // epilogue: fp32 direct
    const int cr0 = m0 + wr * 128 + ((lane >> 4) << 2);
    const int cc0 = n0 + wc * 64 + (lane & 15);
    float* Cg = C32 + (size_t)z * sC;
#pragma unroll
    for (int mi = 0; mi < 8; ++mi)
#pragma unroll
        for (int ni = 0; ni < 4; ++ni)
#pragma unroll
            for (int j = 0; j < 4; ++j)
                Cg[(size_t)(cr0 + mi * 16 + j) * N + cc0 + ni * 16] = acc[mi][ni][j];
#undef GLL16
#undef STAGE_A
#undef STAGE_B
#undef SBAR
#undef LGKM0
#undef LDA
#undef LDB
#undef MFMA_Q
}

// ===========================================================================
// gemm_bw: 128x128 TN GEMM, 256 threads / 4 waves (2M x 2N), per-wave 64x64,
// BK=32, 3-buffer LDS ring (48 KB -> 3 blocks/CU), one phase per K-tile.
// Swizzle ([*][32] tiles): stage granule cl = g^((g>>3)&3); read elem XOR
// exr = ((lane>>1)&3)<<3.
// Phase T (buf b0=T%3): {vmcnt(4); bar} read 4 A + 4 B frags from b0 |
// STAGE(T+2)->b2 | lgkm0 | prio 16 MFMA. Rotate.
//  vmcnt: stage = 4 GLLs; at boundary outstanding <= {stage(T),stage(T+1)};
//  vmcnt(4) leaves stage(T+1) -> stage(T) landed. Tail vmcnt(0).
//  Ring safety: stage(T+2) targets buf[(T-1)%3], last read retired at
//  lgkm0(T-1) before this phase's barrier. K ascending 32-chunks.
// EPI: 1 = exp(acc+bias)->bf16 LDS-coalesced (proj; z==2 -> Calt);
//      2 = fp32 direct (out2); 3 = plain bf16 LDS-coalesced (Mt).
// ===========================================================================
template<int EPI>
__global__ __launch_bounds__(256, 3) void gemm_bw(
    const u16* __restrict__ Ap, const u16* __restrict__ Bp,
    float* __restrict__ C32, u16* __restrict__ C16, u16* __restrict__ Calt,
    const float* __restrict__ bias,
    int N, int K, long long sA, long long sB, long long sC)
{
    constexpr int BUF = 8192;               // ring stride elems (A 4096 + B 4096)
    __shared__ __align__(16) u16 lds[3 * BUF];   // 48 KiB

    const int tid  = threadIdx.x;
    const int lane = tid & 63;
    const int w    = tid >> 6;
    const int wr   = w >> 1, wc = w & 1;    // 2M x 2N waves

    const int gx  = gridDim.x;
    const int tot = gx * gridDim.y;
    const int lin = blockIdx.y * gx + blockIdx.x;
    const int vlin = (lin & 7) * (tot >> 3) + (lin >> 3);
    const int bx = vlin % gx, by = vlin / gx;
    const int m0 = by * 128, n0 = bx * 128;
    const int z  = blockIdx.z;

    const u16* Ag = Ap + (size_t)z * sA;
    const u16* Bg = Bp + (size_t)z * sB;

    // staging: granule g = ld*256 + tid; cl = g ^ ((g>>3)&3) = ld*256 + cltid
    const int cltid = tid ^ ((tid >> 3) & 3);
    const int crow  = cltid >> 2;           // row within 64-row chunk
    const int ce    = (cltid & 3) * 8;      // col element 0/8/16/24

    // frag reads
    const int exr = ((lane >> 1) & 3) << 3;
    const int ar0 = (wr * 64 + (lane & 15)) * 32 + (lane >> 4) * 8;
    const int br0 = (wc * 64 + (lane & 15)) * 32 + (lane >> 4) * 8;

#define GLLW(gsrc, ldsoff)                                                     \
    __builtin_amdgcn_global_load_lds(                                          \
        (__attribute__((address_space(1))) void*)(uintptr_t)(gsrc),            \
        (__attribute__((address_space(3))) void*)&lds[ldsoff], 16, 0, 0)

#define STAGE(buf, T)                                                          \
    do {                                                                       \
        _Pragma("unroll") for (int ld = 0; ld < 2; ++ld)                       \
            GLLW(Ag + (size_t)(m0 + ld * 64 + crow) * K + (T) * 32 + ce,       \
                 (buf) + ld * 2048 + tid * 8);                                 \
        _Pragma("unroll") for (int ld = 0; ld < 2; ++ld)                       \
            GLLW(Bg + (size_t)(n0 + ld * 64 + crow) * K + (T) * 32 + ce,       \
                 (buf) + 4096 + ld * 2048 + tid * 8);                          \
    } while (0)

#define LGKM0B do { asm volatile("s_waitcnt lgkmcnt(0)" ::: "memory");         \
                    __builtin_amdgcn_sched_barrier(0); } while (0)

    f32x4 acc[4][4];
#pragma unroll
    for (int i = 0; i < 4; ++i)
#pragma unroll
        for (int j = 0; j < 4; ++j) acc[i][j] = (f32x4)0.0f;

    bf16x8 afr[4], bfr[4];

    const int nt = K >> 5;

    int b0 = 0, b1 = BUF, b2 = 2 * BUF;
    STAGE(b0, 0); STAGE(b1, 1);

    for (int T = 0; T < nt; ++T) {
        if (T + 1 < nt) asm volatile("s_waitcnt vmcnt(4)" ::: "memory");
        else            asm volatile("s_waitcnt vmcnt(0)" ::: "memory");
        asm volatile("s_barrier" ::: "memory");
#pragma unroll
        for (int mi = 0; mi < 4; ++mi)
            afr[mi] = __builtin_bit_cast(bf16x8,
                *(const i32x4*)&lds[b0 + ((ar0 + mi * 512) ^ exr)]);
#pragma unroll
        for (int ni = 0; ni < 4; ++ni)
            bfr[ni] = __builtin_bit_cast(bf16x8,
                *(const i32x4*)&lds[b0 + 4096 + ((br0 + ni * 512) ^ exr)]);
        if (T + 2 < nt) STAGE(b2, T + 2);
        LGKM0B;
        __builtin_amdgcn_s_setprio(1);
#pragma unroll
        for (int mi = 0; mi < 4; ++mi)
#pragma unroll
            for (int ni = 0; ni < 4; ++ni)
                acc[mi][ni] = __builtin_amdgcn_mfma_f32_16x16x32_bf16(
                    afr[mi], bfr[ni], acc[mi][ni], 0, 0, 0);
        __builtin_amdgcn_s_setprio(0);
        int tmp = b0; b0 = b1; b1 = b2; b2 = tmp;
    }

    // ---- epilogue ----
    // C row = m0 + wr*64 + mi*16 + (lane>>4)*4 + j
    // C col = n0 + wc*64 + ni*16 + (lane&15)
    if constexpr (EPI == 1 || EPI == 3) {      // bf16 via LDS, coalesced
        u16* sE = lds;                         // [128][136] u16 (34.8 KB < 48 KB)
        u16* Cb;
        const int colb = wc * 64 + (lane & 15);
        float bv[4];
        if constexpr (EPI == 1) {
            Cb = (z == 2) ? Calt : (C16 + (size_t)z * sC);
#pragma unroll
            for (int ni = 0; ni < 4; ++ni)
                bv[ni] = bias[(size_t)z * 1024 + n0 + colb + ni * 16];
        } else {
            Cb = C16 + (size_t)z * sC;
        }
        const int wrow0 = wr * 64 + ((lane >> 4) << 2);
        __syncthreads();                       // loop drained: vmcnt(0)+lgkm0
#pragma unroll
        for (int mi = 0; mi < 4; ++mi)
#pragma unroll
            for (int ni = 0; ni < 4; ++ni)
#pragma unroll
                for (int j = 0; j < 4; ++j) {
                    float vv = acc[mi][ni][j];
                    if constexpr (EPI == 1) vv = __expf(vv + bv[ni]);
                    sE[(wrow0 + mi * 16 + j) * 136 + colb + ni * 16] = f2b(vv);
                }
        __syncthreads();
        const int rr = tid >> 2, c0 = (tid & 3) * 8;
#pragma unroll
        for (int rb = 0; rb < 2; ++rb) {
            int row = rb * 64 + rr;
#pragma unroll
            for (int i = 0; i < 4; ++i) {
                i32x4 vv = *(const i32x4*)&sE[row * 136 + c0 + i * 32];
                *(i32x4*)&Cb[(size_t)(m0 + row) * N + n0 + c0 + i * 32] = vv;
            }
        }
    } else {                                   // fp32 direct
        float* Cg = C32 + (size_t)z * sC;
        const int cr0 = m0 + wr * 64 + ((lane >> 4) << 2);
        const int cc0 = n0 + wc * 64 + (lane & 15);
#pragma unroll
        for (int mi = 0; mi < 4; ++mi)
#pragma unroll
            for (int ni = 0; ni < 4; ++ni)
#pragma unroll
                for (int j = 0; j < 4; ++j)
                    Cg[(size_t)(cr0 + mi * 16 + j) * N + cc0 + ni * 16] =
                        acc[mi][ni][j];
    }
#undef GLLW
#undef STAGE
#undef LGKM0B
}

// ---- fused: row softmax (qE) + column partials (kE, vE) --------------------
__global__ __launch_bounds__(256) void sm_partials(
    u16* __restrict__ qE, const u16* __restrict__ kE, const u16* __restrict__ vE,
    float* __restrict__ kpart, float* __restrict__ vpart)
{
    int bid = blockIdx.x, t = threadIdx.x;
    if (bid < 8192) {                          // row softmax over D=1024
        u16* p = qE + (size_t)bid * 1024;
        ushort4 v = *(ushort4*)&p[t * 4];
        float e0 = b2f(v.x), e1 = b2f(v.y), e2 = b2f(v.z), e3 = b2f(v.w);
        float s = (e0 + e1) + (e2 + e3);
#pragma unroll
        for (int off = 32; off; off >>= 1) s += __shfl_down(s, off);
        __shared__ float red[4];
        if ((t & 63) == 0) red[t >> 6] = s;
        __syncthreads();
        float inv = 1.0f / ((red[0] + red[1]) + (red[2] + red[3]));
        ushort4 o;
        o.x = f2b(e0 * inv); o.y = f2b(e1 * inv);
        o.z = f2b(e2 * inv); o.w = f2b(e3 * inv);
        *(ushort4*)&p[t * 4] = o;
    } else {                                   // column partials, 128-row chunks
        int j = bid - 8192;
        const u16* d; float* part;
        if (j < 64) { d = kE; part = kpart; } else { d = vE; part = vpart; j -= 64; }
        int b = j >> 4, c = j & 15;
        const u16* base = d + ((size_t)b * 2048 + c * 128) * 1024 + t * 4;
        float a0 = 0, a1 = 0, a2 = 0, a3 = 0;
        for (int s = 0; s < 128; ++s) {
            ushort4 v = *(const ushort4*)(base + (size_t)s * 1024);
            a0 += b2f(v.x); a1 += b2f(v.y); a2 += b2f(v.z); a3 += b2f(v.w);
        }
        *(float4*)(part + ((size_t)(b * 16 + c)) * 1024 + t * 4) = make_float4(a0, a1, a2, a3);
    }
}

// ---- fused: reduce partials -> kinv, vinv ---------------------------------
__global__ __launch_bounds__(256) void col_reduce2(
    const float* __restrict__ kpart, const float* __restrict__ vpart,
    float* __restrict__ kinv, float* __restrict__ vinv)
{
    int bid = blockIdx.x;
    const float* part; float* inv; float mult;
    if (bid < 16) { part = kpart; inv = kinv; mult = 0.03125f; }
    else          { part = vpart; inv = vinv; mult = 1.0f; bid -= 16; }
    int idx = bid * 256 + threadIdx.x;         // 0..4095 over (b,e)
    int b = idx >> 10, e = idx & 1023;
    float s = 0;
    for (int c = 0; c < 16; ++c) s += part[((size_t)(b * 16 + c)) * 1024 + e];
    inv[idx] = mult / s;
}

// ---- norm+transpose, tile-owned (race-free):
//   j<2048: k-tile — normalize kE in place AND write kpT[b][e][s]
//   else  : v-tile — write vpT[b][e][s] (vE stays raw; unused afterwards)
__global__ __launch_bounds__(256) void norm_all(
    u16* __restrict__ kE, const float* __restrict__ kinv, u16* __restrict__ kpT,
    u16* __restrict__ vE, const float* __restrict__ vinv, u16* __restrict__ vpT)
{
    __shared__ __align__(16) u16 tile[64][68];
    int j = blockIdx.x, t = threadIdx.x;
    const bool isK = j < 2048;
    if (!isK) j -= 2048;
    int b = j >> 9, y = (j >> 5) & 15, x = j & 31;
    int s0 = x * 64, e0 = y * 64;
    int lr = t >> 4, lc = (t & 15) * 4;

    u16* src = isK ? kE : vE;
    const float* inv = isK ? kinv : vinv;
    float4 iv = *(const float4*)(inv + b * 1024 + e0 + lc);
#pragma unroll
    for (int i = 0; i < 4; ++i) {
        int sr = i * 16 + lr;
        u16* p = src + ((size_t)b * 2048 + s0 + sr) * 1024 + e0 + lc;
        ushort4 v = *(const ushort4*)p;
        v.x = f2b(b2f(v.x) * iv.x); v.y = f2b(b2f(v.y) * iv.y);
        v.z = f2b(b2f(v.z) * iv.z); v.w = f2b(b2f(v.w) * iv.w);
        if (isK) *(ushort4*)p = v;             // in-place normalized kp
        tile[sr][lc] = v.x; tile[sr][lc + 1] = v.y;
        tile[sr][lc + 2] = v.z; tile[sr][lc + 3] = v.w;
    }
    __syncthreads();
    u16* dst = isK ? kpT : vpT;
#pragma unroll
    for (int i = 0; i < 4; ++i) {
        int er = i * 16 + lr;
        ushort4 v;
        v.x = tile[lc + 0][er]; v.y = tile[lc + 1][er];
        v.z = tile[lc + 2][er]; v.w = tile[lc + 3][er];
        *(ushort4*)(dst + ((size_t)b * 1024 + e0 + er) * 2048 + s0 + lc) = v;
    }
}

extern "C" void kernel_launch(void* const* d_in, const int* in_sizes, int n_in,
                              void* d_out, int out_size, void* d_ws, size_t ws_size,
                              hipStream_t stream)
{
    const float* q  = (const float*)d_in[0];
    const float* k  = (const float*)d_in[1];
    const float* v  = (const float*)d_in[2];
    const float* Wq = (const float*)d_in[3];
    const float* bq = (const float*)d_in[4];
    const float* Wk = (const float*)d_in[5];
    const float* bk = (const float*)d_in[6];
    const float* Wv = (const float*)d_in[7];
    const float* bv = (const float*)d_in[8];

    float* out  = (float*)d_out;          // [4,2048,1024] fp32
    float* attn = out + 8388608;          // [4,2048,2048] fp32

    u16* wsU = (u16*)d_ws;
    u16* qE   = wsU;                      // R0: exp'd q logits -> qp
    u16* kE   = wsU + 8388608;            // R1: exp'd k logits -> kp
    u16* Wb   = wsU + 16777216;           // R2: Wqb|Wkb|Wvb (stride 1M)
    u16* qb   = wsU + 25165824;           // R3: q bf16 (dead after proj)
    u16* kb   = wsU + 33554432;           // R4: k bf16 (dead after proj)
    u16* vb   = wsU + 41943040;           // R4+8.4M: v bf16 (dead after proj)
    u16* vpT  = wsU + 25165824;           // R3 after proj: vpT [4,1024,2048]
    u16* kpT  = wsU + 33554432;           // R4 after proj: kpT [4,1024,2048]
    u16* Mt   = wsU + 41943040;           // R4+8.4M after proj: Mt [4,1024,1024]
    u16* vE   = (u16*)attn;               // d_out attn region as scratch

    float* tail  = (float*)(wsU + 50331648);
    float* kpart = tail;                  // [4,16,1024]
    float* vpart = tail + 65536;
    float* kinv  = tail + 131072;         // [4,1024]
    float* vinv  = tail + 135168;
    float* biasCat = tail + 139264;       // [3,1024] bq|bk|bv

    const long long SD = 2048LL * 1024, SS = 2048LL * 2048, DS = 1024LL * 2048;

    // ---- 1: convert inputs + weights to bf16, gather biases ----
    cvt_all<<<dim3(27649), dim3(256), 0, stream>>>(
        (const float4*)q, (const float4*)k, (const float4*)v,
        (const float4*)Wq, (const float4*)Wk, (const float4*)Wv,
        bq, bk, bv,
        (ushort4*)qb, (ushort4*)kb, (ushort4*)vb, (ushort4*)Wb, biasCat);

    // ---- 2: batched projections (128x128, 3/CU): z=0/1/2 -> qE, kE, vE ----
    gemm_bw<1><<<dim3(8, 64, 3), dim3(256), 0, stream>>>(
        qb, Wb, nullptr, qE, vE, biasCat,
        1024, 1024, 8388608LL, 1048576LL, 8388608LL);

    // ---- 3: row softmax (qE) + col partials (kE, vE) ----
    sm_partials<<<dim3(8320), dim3(256), 0, stream>>>(qE, kE, vE, kpart, vpart);

    // ---- 4: reduce -> kinv (x 1/32), vinv ----
    col_reduce2<<<dim3(32), dim3(256), 0, stream>>>(kpart, vpart, kinv, vinv);

    // ---- 5: normalize: kE in place + kpT; vpT ----
    norm_all<<<dim3(4096), dim3(256), 0, stream>>>(kE, kinv, kpT, vE, vinv, vpT);

    // ---- 6: Mt[d2,d1] = sum_s vp[s,d2] kp[s,d1]  (TN: A=vpT, B=kpT) ----
    gemm_bw<3><<<dim3(8, 8, 4), dim3(256), 0, stream>>>(
        vpT, kpT, nullptr, Mt, nullptr, nullptr,
        1024, 2048, DS, DS, 1048576LL);

    // ---- 7: attn = qp @ kp^T -> fp32 d_out (overwrites vE scratch) ----
    gemm256_attn<<<dim3(8, 8, 4), dim3(512), 0, stream>>>(
        qE, kE, attn, 2048, 1024, SD, SD, SS);

    // ---- 8: out = qp @ Mt^T -> fp32 d_out  (= attn @ vp by associativity) ----
    gemm_bw<2><<<dim3(8, 16, 4), dim3(256), 0, stream>>>(
        qE, Mt, out, nullptr, nullptr, nullptr,
        1024, 1024, SD, 1048576LL, SD);
}